// Round 6
// baseline (303.152 us; speedup 1.0000x reference)
//
#include <hip/hip_runtime.h>

typedef unsigned short ushort_t;
typedef __attribute__((ext_vector_type(8))) short bf16x8;
typedef __attribute__((ext_vector_type(4))) float f32x4;
typedef __attribute__((ext_vector_type(8))) unsigned short u16x8;

#define AS1 __attribute__((address_space(1)))
#define AS3 __attribute__((address_space(3)))

// RNE float -> bf16
static __device__ __forceinline__ unsigned short f2bf(float f) {
    unsigned u = __float_as_uint(f);
    u += 0x7fffu + ((u >> 16) & 1u);
    return (unsigned short)(u >> 16);
}

// ---------------------------------------------------------------------------
// prep: per-row sum-of-squares + fp32 -> bf16. One wave per row (C=512).
// ---------------------------------------------------------------------------
__global__ __launch_bounds__(256) void prep_kernel(
    const float* __restrict__ src, ushort_t* __restrict__ dst,
    float* __restrict__ sq)
{
    const int row  = blockIdx.x * 4 + (threadIdx.x >> 6);
    const int lane = threadIdx.x & 63;
    const float4* s = (const float4*)(src + (size_t)row * 512);
    float4 v0 = s[lane * 2 + 0];
    float4 v1 = s[lane * 2 + 1];
    float ss = v0.x*v0.x + v0.y*v0.y + v0.z*v0.z + v0.w*v0.w
             + v1.x*v1.x + v1.y*v1.y + v1.z*v1.z + v1.w*v1.w;
    #pragma unroll
    for (int m = 32; m >= 1; m >>= 1) ss += __shfl_xor(ss, m);
    if (lane == 0) sq[row] = ss;
    u16x8 o;
    o[0]=f2bf(v0.x); o[1]=f2bf(v0.y); o[2]=f2bf(v0.z); o[3]=f2bf(v0.w);
    o[4]=f2bf(v1.x); o[5]=f2bf(v1.y); o[6]=f2bf(v1.z); o[7]=f2bf(v1.w);
    *(u16x8*)(dst + (size_t)row * 512 + lane * 8) = o;
}

// ---------------------------------------------------------------------------
// gemm_main: cross GEMM (M=512, N=65536, K=512), 128x128 tile, BK=64,
// DOUBLE-BUFFERED 2-phase prefetch (T3 minimum recipe): issue next tile's
// A global_load_lds + B reg-loads BEFORE computing current; cvt+ds_write
// after the MFMAs; ONE barrier per K-step.
// Epilogue: inline x_sq, inv = sqrt(512)*rsqrt(d2) stored f32 (full-sector
// stores) into the wout region, + deterministic partial row sums.
// ---------------------------------------------------------------------------
__global__ __launch_bounds__(256, 2) void gemm_main(
    const ushort_t* __restrict__ pb, const float* __restrict__ x,
    const float* __restrict__ p_sq, float* __restrict__ invf,
    float* __restrict__ partial, int Nn)
{
    __shared__ __align__(16) ushort_t As[2][8192];   // 2 x 16KB
    __shared__ __align__(16) ushort_t Bs[2][8192];   // 2 x 16KB

    const int tid  = threadIdx.x;
    const int lane = tid & 63, wid = tid >> 6;
    const int wm = wid >> 1, wn = wid & 1;
    const int l15 = lane & 15, l4 = lane >> 4;

    // chunked XCD swizzle (bijective: nwg = 2048, %8 == 0)
    const int nwg = gridDim.x * gridDim.y;
    const int w   = blockIdx.x + gridDim.x * blockIdx.y;
    int orig = w;
    if ((nwg & 7) == 0) orig = (w & 7) * (nwg >> 3) + (w >> 3);
    const int m0 = (orig & 3) * 128;
    const int n0 = (orig >> 2) * 128;
    const int by = orig >> 2;

    f32x4 acc[4][4] = {};
    float ssq[4] = {0.f, 0.f, 0.f, 0.f};
    float4 pf0[4], pf1[4];

#define STAGE_A(buf, kt)                                                     \
    _Pragma("unroll")                                                        \
    for (int it = 0; it < 4; ++it) {                                         \
        const int cbase = it * 256 + wid * 64;                               \
        const int cid   = cbase + lane;                                      \
        const int r     = cid >> 3;                                          \
        const int cl    = (cid & 7) ^ (r & 7);                               \
        const ushort_t* ga = pb + (size_t)(m0 + r) * 512 + (kt) + cl * 8;    \
        __builtin_amdgcn_global_load_lds((const AS1 unsigned int*)ga,        \
            (AS3 unsigned int*)(&As[buf][cbase * 8]), 16, 0, 0);             \
    }

#define LOAD_B(kt)                                                           \
    _Pragma("unroll")                                                        \
    for (int it = 0; it < 4; ++it) {                                         \
        const int r  = it * 32 + (tid >> 3);                                 \
        const int cl = tid & 7;                                              \
        const float4* src =                                                  \
            (const float4*)(x + (size_t)(n0 + r) * 512 + (kt) + cl * 8);     \
        pf0[it] = src[0]; pf1[it] = src[1];                                  \
    }

#define WRITE_B(buf)                                                         \
    _Pragma("unroll")                                                        \
    for (int it = 0; it < 4; ++it) {                                         \
        const int r  = it * 32 + (tid >> 3);                                 \
        const int cl = tid & 7;                                              \
        const float4 f0 = pf0[it], f1 = pf1[it];                             \
        ssq[it] += f0.x*f0.x + f0.y*f0.y + f0.z*f0.z + f0.w*f0.w             \
                 + f1.x*f1.x + f1.y*f1.y + f1.z*f1.z + f1.w*f1.w;            \
        u16x8 o;                                                             \
        o[0]=f2bf(f0.x); o[1]=f2bf(f0.y); o[2]=f2bf(f0.z); o[3]=f2bf(f0.w);  \
        o[4]=f2bf(f1.x); o[5]=f2bf(f1.y); o[6]=f2bf(f1.z); o[7]=f2bf(f1.w);  \
        *(u16x8*)&Bs[buf][(r * 8 + (cl ^ (r & 7))) * 8] = o;                 \
    }

#define COMPUTE(cur)                                                         \
    _Pragma("unroll")                                                        \
    for (int kk = 0; kk < 2; ++kk) {                                         \
        bf16x8 a[4], b[4];                                                   \
        _Pragma("unroll")                                                    \
        for (int mi = 0; mi < 4; ++mi) {                                     \
            const int rr = wm * 64 + mi * 16 + l15;                          \
            const int c  = kk * 4 + l4;                                      \
            a[mi] = *(const bf16x8*)&As[cur][(rr * 8 + (c ^ (rr & 7))) * 8]; \
        }                                                                    \
        _Pragma("unroll")                                                    \
        for (int ni = 0; ni < 4; ++ni) {                                     \
            const int rr = wn * 64 + ni * 16 + l15;                          \
            const int c  = kk * 4 + l4;                                      \
            b[ni] = *(const bf16x8*)&Bs[cur][(rr * 8 + (c ^ (rr & 7))) * 8]; \
        }                                                                    \
        _Pragma("unroll")                                                    \
        for (int mi = 0; mi < 4; ++mi)                                       \
            _Pragma("unroll")                                                \
            for (int ni = 0; ni < 4; ++ni)                                   \
                acc[mi][ni] = __builtin_amdgcn_mfma_f32_16x16x32_bf16(       \
                    a[mi], b[ni], acc[mi][ni], 0, 0, 0);                     \
    }

    // prologue: stage tile 0 into buf 0
    LOAD_B(0)
    STAGE_A(0, 0)
    WRITE_B(0)
    __syncthreads();

    #pragma unroll
    for (int t = 0; t < 7; ++t) {
        const int cur = t & 1;
        LOAD_B((t + 1) * 64)          // issue next B loads (regs, async)
        STAGE_A(cur ^ 1, (t + 1) * 64) // issue next A direct-to-LDS (async)
        COMPUTE(cur)                   // MFMA on current buffer
        WRITE_B(cur ^ 1)               // cvt + ds_write next B
        __syncthreads();               // next buffer ready; readers drained
    }
    COMPUTE(1)                         // t = 7 on buf 1
    __syncthreads();

    // inline x_sq: 8 consecutive lanes share one x row
    float* xsq_s = (float*)&Bs[0][0];
    #pragma unroll
    for (int it = 0; it < 4; ++it) {
        float s = ssq[it];
        s += __shfl_xor(s, 1); s += __shfl_xor(s, 2); s += __shfl_xor(s, 4);
        if ((tid & 7) == 0) xsq_s[it * 32 + (tid >> 3)] = s;
    }
    __syncthreads();

    // D frag (m89): col = lane&15 (-> n), row = (lane>>4)*4 + j (-> p)
    float psum[4][4] = {};
    #pragma unroll
    for (int mi = 0; mi < 4; ++mi) {
        const int pbase = m0 + wm * 64 + mi * 16 + l4 * 4;
        const f32x4 ps4 = *(const f32x4*)(p_sq + pbase);
        #pragma unroll
        for (int ni = 0; ni < 4; ++ni) {
            const int nl = wn * 64 + ni * 16 + l15;
            const float xs = xsq_s[nl];
            #pragma unroll
            for (int j = 0; j < 4; ++j) {
                float d2 = ps4[j] + xs - 2.0f * acc[mi][ni][j];
                d2 = fmaxf(d2, 1e-20f);
                const float iv = 22.62741699796952f * rsqrtf(d2);
                psum[mi][j] += iv;
                invf[(size_t)(pbase + j) * Nn + n0 + nl] = iv;
            }
        }
    }
    #pragma unroll
    for (int mi = 0; mi < 4; ++mi)
        #pragma unroll
        for (int j = 0; j < 4; ++j) {
            float s = psum[mi][j];
            s += __shfl_xor(s, 1); s += __shfl_xor(s, 2);
            s += __shfl_xor(s, 4); s += __shfl_xor(s, 8);
            psum[mi][j] = s;
        }
    float* sp = (float*)&As[0][0];  // [128 rows][2 wn]
    if (l15 == 0) {
        #pragma unroll
        for (int mi = 0; mi < 4; ++mi)
            #pragma unroll
            for (int j = 0; j < 4; ++j)
                sp[(wm * 64 + mi * 16 + l4 * 4 + j) * 2 + wn] = psum[mi][j];
    }
    __syncthreads();
    if (tid < 128)
        partial[(size_t)(m0 + tid) * gridDim.y + by] =
            sp[tid * 2] + sp[tid * 2 + 1];

#undef STAGE_A
#undef LOAD_B
#undef WRITE_B
#undef COMPUTE
}

// ---------------------------------------------------------------------------
// rowsum: partials per prototype -> reciprocal (deterministic tree)
// ---------------------------------------------------------------------------
__global__ __launch_bounds__(256) void rowsum_kernel(
    const float* __restrict__ partial, float* __restrict__ rcp, int nb)
{
    const int p = blockIdx.x;
    const int tid = threadIdx.x;
    float s = 0.0f;
    for (int i = tid; i < nb; i += 256) s += partial[(size_t)p * nb + i];
    #pragma unroll
    for (int m = 32; m >= 1; m >>= 1) s += __shfl_xor(s, m);
    __shared__ float red[4];
    if ((tid & 63) == 0) red[tid >> 6] = s;
    __syncthreads();
    if (tid == 0) rcp[p] = 1.0f / (red[0] + red[1] + red[2] + red[3]);
}

// ---------------------------------------------------------------------------
// finalize: w = inv * rcp[p] written IN PLACE over inv (same element, no
// race), plus x_out[n][c] = w[c][n] * x[n][c] via 64x64 LDS transpose.
// (R1-verified structure.)
// ---------------------------------------------------------------------------
__global__ __launch_bounds__(256) void finalize_kernel(
    const float* __restrict__ x, float* __restrict__ w,
    const float* __restrict__ rcp, float* __restrict__ xout, int Nn)
{
    __shared__ float T[64][65];
    const int tid = threadIdx.x;
    const int tx = tid & 15, ty = tid >> 4;
    const int p0 = blockIdx.x * 64, n0 = blockIdx.y * 64;
    #pragma unroll
    for (int rr = 0; rr < 4; ++rr) {
        const int pl = ty + rr * 16;
        const size_t idx = (size_t)(p0 + pl) * Nn + n0 + tx * 4;
        const float4 iv = *(const float4*)(w + idx);
        const float rc = rcp[p0 + pl];
        float4 wv;
        wv.x = iv.x * rc; wv.y = iv.y * rc; wv.z = iv.z * rc; wv.w = iv.w * rc;
        *(float4*)(w + idx) = wv;
        T[tx * 4 + 0][pl] = wv.x;
        T[tx * 4 + 1][pl] = wv.y;
        T[tx * 4 + 2][pl] = wv.z;
        T[tx * 4 + 3][pl] = wv.w;
    }
    __syncthreads();
    #pragma unroll
    for (int rr = 0; rr < 4; ++rr) {
        const int nl = ty + rr * 16;
        const size_t ix = (size_t)(n0 + nl) * 512 + p0 + tx * 4;
        const float4 xv = *(const float4*)(x + ix);
        float4 ov;
        ov.x = xv.x * T[nl][tx * 4 + 0];
        ov.y = xv.y * T[nl][tx * 4 + 1];
        ov.z = xv.z * T[nl][tx * 4 + 2];
        ov.w = xv.w * T[nl][tx * 4 + 3];
        *(float4*)(xout + ix) = ov;
    }
}

// ===========================================================================
// Fallback path (tiny d_ws): R2-verified structure, scratch in x_out half.
// ===========================================================================
template<int MODE>
__global__ __launch_bounds__(256) void gemm_old(
    const ushort_t* __restrict__ pb, const ushort_t* __restrict__ xb,
    const float* __restrict__ p_sq, const float* __restrict__ x_sq,
    const float* __restrict__ rcp,
    float* __restrict__ wout, float* __restrict__ partial, int Nn)
{
    __shared__ __align__(16) char smem[33280];
    ushort_t* As = (ushort_t*)smem;
    ushort_t* Bs = (ushort_t*)(smem + 16384);
    const int tid  = threadIdx.x;
    const int lane = tid & 63, wid = tid >> 6;
    const int wm = wid >> 1, wn = wid & 1;
    const int l15 = lane & 15, l4 = lane >> 4;
    const int m0 = blockIdx.x * 128;
    const int n0 = blockIdx.y * 128;
    f32x4 acc[4][4] = {};
    for (int kt = 0; kt < 512; kt += 64) {
        #pragma unroll
        for (int it = 0; it < 4; ++it) {
            const int cbase = it * 256 + wid * 64;
            const int cid   = cbase + lane;
            const int r     = cid >> 3;
            const int cl    = (cid & 7) ^ (r & 7);
            const ushort_t* ga = pb + (size_t)(m0 + r) * 512 + kt + cl * 8;
            __builtin_amdgcn_global_load_lds((const AS1 unsigned int*)ga,
                (AS3 unsigned int*)(As + cbase * 8), 16, 0, 0);
            const ushort_t* gb = xb + (size_t)(n0 + r) * 512 + kt + cl * 8;
            __builtin_amdgcn_global_load_lds((const AS1 unsigned int*)gb,
                (AS3 unsigned int*)(Bs + cbase * 8), 16, 0, 0);
        }
        __syncthreads();
        #pragma unroll
        for (int kk = 0; kk < 2; ++kk) {
            bf16x8 a[4], b[4];
            #pragma unroll
            for (int mi = 0; mi < 4; ++mi) {
                const int rr = wm * 64 + mi * 16 + l15;
                const int c  = kk * 4 + l4;
                a[mi] = *(const bf16x8*)&As[(rr * 8 + (c ^ (rr & 7))) * 8];
            }
            #pragma unroll
            for (int ni = 0; ni < 4; ++ni) {
                const int rr = wn * 64 + ni * 16 + l15;
                const int c  = kk * 4 + l4;
                b[ni] = *(const bf16x8*)&Bs[(rr * 8 + (c ^ (rr & 7))) * 8];
            }
            #pragma unroll
            for (int mi = 0; mi < 4; ++mi)
                #pragma unroll
                for (int ni = 0; ni < 4; ++ni)
                    acc[mi][ni] = __builtin_amdgcn_mfma_f32_16x16x32_bf16(
                        a[mi], b[ni], acc[mi][ni], 0, 0, 0);
        }
        __syncthreads();
    }
    if (MODE == 0) {
        float psum[4][4] = {};
        #pragma unroll
        for (int mi = 0; mi < 4; ++mi) {
            const int pbase = m0 + wm * 64 + mi * 16 + l4 * 4;
            const f32x4 ps4 = *(const f32x4*)(p_sq + pbase);
            #pragma unroll
            for (int ni = 0; ni < 4; ++ni) {
                const int n = n0 + wn * 64 + ni * 16 + l15;
                const float xs = x_sq[n];
                #pragma unroll
                for (int j = 0; j < 4; ++j) {
                    float d2 = ps4[j] + xs - 2.0f * acc[mi][ni][j];
                    d2 = fmaxf(d2, 1e-20f);
                    psum[mi][j] += 22.62741699796952f * rsqrtf(d2);
                }
            }
        }
        #pragma unroll
        for (int mi = 0; mi < 4; ++mi)
            #pragma unroll
            for (int j = 0; j < 4; ++j) {
                float s = psum[mi][j];
                s += __shfl_xor(s, 1); s += __shfl_xor(s, 2);
                s += __shfl_xor(s, 4); s += __shfl_xor(s, 8);
                psum[mi][j] = s;
            }
        float* sp = (float*)smem;
        if (l15 == 0) {
            #pragma unroll
            for (int mi = 0; mi < 4; ++mi)
                #pragma unroll
                for (int j = 0; j < 4; ++j)
                    sp[(wm * 64 + mi * 16 + l4 * 4 + j) * 2 + wn] = psum[mi][j];
        }
        __syncthreads();
        if (tid < 128)
            partial[(size_t)(m0 + tid) * gridDim.y + blockIdx.y] =
                sp[tid * 2] + sp[tid * 2 + 1];
    } else {
        #pragma unroll
        for (int mi = 0; mi < 4; ++mi) {
            const int pbase = m0 + wm * 64 + mi * 16 + l4 * 4;
            const f32x4 ps4 = *(const f32x4*)(p_sq + pbase);
            const f32x4 rc4 = *(const f32x4*)(rcp + pbase);
            #pragma unroll
            for (int ni = 0; ni < 4; ++ni) {
                const int n = n0 + wn * 64 + ni * 16 + l15;
                const float xs = x_sq[n];
                #pragma unroll
                for (int j = 0; j < 4; ++j) {
                    float d2 = ps4[j] + xs - 2.0f * acc[mi][ni][j];
                    d2 = fmaxf(d2, 1e-20f);
                    wout[(size_t)(pbase + j) * Nn + n] =
                        22.62741699796952f * rsqrtf(d2) * rc4[j];
                }
            }
        }
    }
}

__global__ __launch_bounds__(256) void finalize2_kernel(
    const float* __restrict__ x, const float* __restrict__ w,
    float* __restrict__ xout, int Nn)
{
    __shared__ float T[64][65];
    const int tid = threadIdx.x;
    const int tx = tid & 15, ty = tid >> 4;
    const int p0 = blockIdx.x * 64, n0 = blockIdx.y * 64;
    #pragma unroll
    for (int rr = 0; rr < 4; ++rr) {
        const int pl = ty + rr * 16;
        const f32x4 wv = *(const f32x4*)(w + (size_t)(p0 + pl) * Nn + n0 + tx * 4);
        T[tx * 4 + 0][pl] = wv[0];
        T[tx * 4 + 1][pl] = wv[1];
        T[tx * 4 + 2][pl] = wv[2];
        T[tx * 4 + 3][pl] = wv[3];
    }
    __syncthreads();
    #pragma unroll
    for (int rr = 0; rr < 4; ++rr) {
        const int nl = ty + rr * 16;
        const size_t ix = (size_t)(n0 + nl) * 512 + p0 + tx * 4;
        const f32x4 xv = *(const f32x4*)(x + ix);
        f32x4 ov;
        ov[0] = xv[0] * T[nl][tx * 4 + 0];
        ov[1] = xv[1] * T[nl][tx * 4 + 1];
        ov[2] = xv[2] * T[nl][tx * 4 + 2];
        ov[3] = xv[3] * T[nl][tx * 4 + 3];
        *(f32x4*)(xout + ix) = ov;
    }
}

// ---------------------------------------------------------------------------
// Host launch.
//  main (ws >= ~1.8 MB): prep_p -> gemm_main (dbuf prefetch, inv f32 into
//  wout region) -> rowsum -> finalize (rescale in place + transpose x_out).
//  fallback: R2 structure.
// ---------------------------------------------------------------------------
extern "C" void kernel_launch(void* const* d_in, const int* in_sizes, int n_in,
                              void* d_out, int out_size, void* d_ws, size_t ws_size,
                              hipStream_t stream)
{
    const float* x     = (const float*)d_in[0];
    const float* proto = (const float*)d_in[1];
    const int C = 512, P = 512;
    const int N = in_sizes[0] / C;            // 65536
    const int NB = N / 128;

    float* xout = (float*)d_out;              // N*C floats
    float* wout = xout + (size_t)N * C;       // P*N floats (inv, then w)

    const size_t pbf_b = (size_t)P * C * 2;   // 512 KiB
    const size_t need  = pbf_b + (size_t)P * 4 + (size_t)N * 4
                       + (size_t)P * NB * 4 + (size_t)P * 4;   // ~1.8 MiB

    if (ws_size >= need) {
        char* scr = (char*)d_ws;
        ushort_t* pbf  = (ushort_t*)scr;
        float*    p_sq = (float*)(scr + pbf_b);
        float*    part = p_sq + P;
        float*    rcp  = part + (size_t)P * NB;

        prep_kernel<<<P / 4, 256, 0, stream>>>(proto, pbf, p_sq);
        gemm_main<<<dim3(P / 128, NB), 256, 0, stream>>>(
            pbf, x, p_sq, wout, part, N);
        rowsum_kernel<<<P, 256, 0, stream>>>(part, rcp, NB);
        finalize_kernel<<<dim3(P / 64, N / 64), 256, 0, stream>>>(
            x, wout, rcp, xout, N);
    } else {
        char* scr = (char*)d_out;             // scratch inside x_out half
        const size_t xb_b = (size_t)N * C * 2;
        ushort_t* xb   = (ushort_t*)scr;
        ushort_t* pbf  = (ushort_t*)(scr + xb_b);
        float*    x_sq = (float*)(scr + xb_b + pbf_b);
        float*    p_sq = x_sq + N;
        float*    part = p_sq + P;
        float*    rcp  = (float*)d_ws;

        prep_kernel<<<N / 4, 256, 0, stream>>>(x, xb, x_sq);
        prep_kernel<<<P / 4, 256, 0, stream>>>(proto, pbf, p_sq);
        gemm_old<0><<<dim3(P / 128, NB), 256, 0, stream>>>(
            pbf, xb, p_sq, x_sq, nullptr, nullptr, part, N);
        rowsum_kernel<<<P, 256, 0, stream>>>(part, rcp, NB);
        gemm_old<2><<<dim3(P / 128, NB), 256, 0, stream>>>(
            pbf, xb, p_sq, x_sq, rcp, wout, nullptr, N);
        finalize2_kernel<<<dim3(P / 64, N / 64), 256, 0, stream>>>(
            x, wout, xout, N);
    }
}

// Round 7
// 209.721 us; speedup vs baseline: 1.4455x; 1.4455x over previous
//
#include <hip/hip_runtime.h>

typedef unsigned short ushort_t;
typedef __attribute__((ext_vector_type(8))) short bf16x8;
typedef __attribute__((ext_vector_type(4))) float f32x4;
typedef __attribute__((ext_vector_type(8))) unsigned short u16x8;

#define AS1 __attribute__((address_space(1)))
#define AS3 __attribute__((address_space(3)))

// RNE float -> bf16
static __device__ __forceinline__ unsigned short f2bf(float f) {
    unsigned u = __float_as_uint(f);
    u += 0x7fffu + ((u >> 16) & 1u);
    return (unsigned short)(u >> 16);
}

// ---------------------------------------------------------------------------
// prep: per-row sum-of-squares + fp32 -> bf16. One wave per row (C=512).
// ---------------------------------------------------------------------------
__global__ __launch_bounds__(256) void prep_kernel(
    const float* __restrict__ src, ushort_t* __restrict__ dst,
    float* __restrict__ sq)
{
    const int row  = blockIdx.x * 4 + (threadIdx.x >> 6);
    const int lane = threadIdx.x & 63;
    const float4* s = (const float4*)(src + (size_t)row * 512);
    float4 v0 = s[lane * 2 + 0];
    float4 v1 = s[lane * 2 + 1];
    float ss = v0.x*v0.x + v0.y*v0.y + v0.z*v0.z + v0.w*v0.w
             + v1.x*v1.x + v1.y*v1.y + v1.z*v1.z + v1.w*v1.w;
    #pragma unroll
    for (int m = 32; m >= 1; m >>= 1) ss += __shfl_xor(ss, m);
    if (lane == 0) sq[row] = ss;
    u16x8 o;
    o[0]=f2bf(v0.x); o[1]=f2bf(v0.y); o[2]=f2bf(v0.z); o[3]=f2bf(v0.w);
    o[4]=f2bf(v1.x); o[5]=f2bf(v1.y); o[6]=f2bf(v1.z); o[7]=f2bf(v1.w);
    *(u16x8*)(dst + (size_t)row * 512 + lane * 8) = o;
}

// ---------------------------------------------------------------------------
// gemm_inv: cross GEMM (M=512, N=65536, K=512), 128x128 tile, BK=64,
// SINGLE-buffered (R4-proven body: VGPR ~116, no scratch spill).
// A (proto bf16): global_load_lds w=16, inverse-swizzled source.
// B (x f32): reg-staged -> bf16 -> swizzled ds_write. Inline x_sq.
// Epilogue: inv = sqrt(512)*rsqrt(d2) stored f32 into the wout region
// (rescaled in place later) + deterministic partial row sums.
// ---------------------------------------------------------------------------
__global__ __launch_bounds__(256, 4) void gemm_inv(
    const ushort_t* __restrict__ pb, const float* __restrict__ x,
    const float* __restrict__ p_sq, float* __restrict__ invf,
    float* __restrict__ partial, int Nn)
{
    __shared__ __align__(16) char smem[33280];   // As+Bs (32KB)
    ushort_t* As = (ushort_t*)smem;
    ushort_t* Bs = (ushort_t*)(smem + 16384);

    const int tid  = threadIdx.x;
    const int lane = tid & 63, wid = tid >> 6;
    const int wm = wid >> 1, wn = wid & 1;
    const int l15 = lane & 15, l4 = lane >> 4;

    // chunked XCD swizzle (bijective: nwg = 2048, %8 == 0)
    const int nwg = gridDim.x * gridDim.y;
    const int w   = blockIdx.x + gridDim.x * blockIdx.y;
    int orig = w;
    if ((nwg & 7) == 0) orig = (w & 7) * (nwg >> 3) + (w >> 3);
    const int m0 = (orig & 3) * 128;
    const int n0 = (orig >> 2) * 128;
    const int by = orig >> 2;

    f32x4 acc[4][4] = {};
    float ssq[4] = {0.f, 0.f, 0.f, 0.f};

    for (int kt = 0; kt < 512; kt += 64) {
        // A: global_load_lds, linear LDS dest + inverse-swizzled source
        #pragma unroll
        for (int it = 0; it < 4; ++it) {
            const int cbase = it * 256 + wid * 64;
            const int cid   = cbase + lane;
            const int r     = cid >> 3;
            const int cl    = (cid & 7) ^ (r & 7);
            const ushort_t* ga = pb + (size_t)(m0 + r) * 512 + kt + cl * 8;
            __builtin_amdgcn_global_load_lds((const AS1 unsigned int*)ga,
                (AS3 unsigned int*)(As + cbase * 8), 16, 0, 0);
        }
        // B: f32 coalesced load -> bf16 -> swizzled ds_write (16B)
        #pragma unroll
        for (int it = 0; it < 4; ++it) {
            const int g  = it * 256 + tid;
            const int r  = g >> 3;
            const int cl = g & 7;
            const float4* src = (const float4*)(x + (size_t)(n0 + r) * 512 + kt + cl * 8);
            const float4 f0 = src[0];
            const float4 f1 = src[1];
            ssq[it] += f0.x*f0.x + f0.y*f0.y + f0.z*f0.z + f0.w*f0.w
                     + f1.x*f1.x + f1.y*f1.y + f1.z*f1.z + f1.w*f1.w;
            u16x8 o;
            o[0]=f2bf(f0.x); o[1]=f2bf(f0.y); o[2]=f2bf(f0.z); o[3]=f2bf(f0.w);
            o[4]=f2bf(f1.x); o[5]=f2bf(f1.y); o[6]=f2bf(f1.z); o[7]=f2bf(f1.w);
            *(u16x8*)&Bs[((size_t)(r * 8 + (cl ^ (r & 7)))) * 8] = o;
        }
        __syncthreads();
        #pragma unroll
        for (int kk = 0; kk < 2; ++kk) {
            bf16x8 a[4], b[4];
            #pragma unroll
            for (int mi = 0; mi < 4; ++mi) {
                const int rr = wm * 64 + mi * 16 + l15;
                const int c  = kk * 4 + l4;
                a[mi] = *(const bf16x8*)&As[(rr * 8 + (c ^ (rr & 7))) * 8];
            }
            #pragma unroll
            for (int ni = 0; ni < 4; ++ni) {
                const int rr = wn * 64 + ni * 16 + l15;
                const int c  = kk * 4 + l4;
                b[ni] = *(const bf16x8*)&Bs[(rr * 8 + (c ^ (rr & 7))) * 8];
            }
            #pragma unroll
            for (int mi = 0; mi < 4; ++mi)
                #pragma unroll
                for (int ni = 0; ni < 4; ++ni)
                    acc[mi][ni] = __builtin_amdgcn_mfma_f32_16x16x32_bf16(
                        a[mi], b[ni], acc[mi][ni], 0, 0, 0);
        }
        __syncthreads();
    }

    // inline x_sq: 8 consecutive lanes share one x row
    float* xsq_s = (float*)(smem + 16384);      // 128 floats (Bs region)
    #pragma unroll
    for (int it = 0; it < 4; ++it) {
        float s = ssq[it];
        s += __shfl_xor(s, 1); s += __shfl_xor(s, 2); s += __shfl_xor(s, 4);
        if ((tid & 7) == 0) xsq_s[it * 32 + (tid >> 3)] = s;
    }
    __syncthreads();

    // D frag (m89): col = lane&15 (-> n), row = (lane>>4)*4 + j (-> p)
    float psum[4][4] = {};
    #pragma unroll
    for (int mi = 0; mi < 4; ++mi) {
        const int pbase = m0 + wm * 64 + mi * 16 + l4 * 4;
        const f32x4 ps4 = *(const f32x4*)(p_sq + pbase);
        #pragma unroll
        for (int ni = 0; ni < 4; ++ni) {
            const int nl = wn * 64 + ni * 16 + l15;
            const float xs = xsq_s[nl];
            #pragma unroll
            for (int j = 0; j < 4; ++j) {
                float d2 = ps4[j] + xs - 2.0f * acc[mi][ni][j];
                d2 = fmaxf(d2, 1e-20f);
                const float iv = 22.62741699796952f * rsqrtf(d2);
                psum[mi][j] += iv;
                invf[(size_t)(pbase + j) * Nn + n0 + nl] = iv;
            }
        }
    }
    #pragma unroll
    for (int mi = 0; mi < 4; ++mi)
        #pragma unroll
        for (int j = 0; j < 4; ++j) {
            float s = psum[mi][j];
            s += __shfl_xor(s, 1); s += __shfl_xor(s, 2);
            s += __shfl_xor(s, 4); s += __shfl_xor(s, 8);
            psum[mi][j] = s;
        }
    float* sp = (float*)smem;  // [128 rows][2 wn] (As region)
    if (l15 == 0) {
        #pragma unroll
        for (int mi = 0; mi < 4; ++mi)
            #pragma unroll
            for (int j = 0; j < 4; ++j)
                sp[(wm * 64 + mi * 16 + l4 * 4 + j) * 2 + wn] = psum[mi][j];
    }
    __syncthreads();
    if (tid < 128)
        partial[(size_t)(m0 + tid) * gridDim.y + by] =
            sp[tid * 2] + sp[tid * 2 + 1];
}

// ---------------------------------------------------------------------------
// rowsum: partials per prototype -> reciprocal (deterministic tree)
// ---------------------------------------------------------------------------
__global__ __launch_bounds__(256) void rowsum_kernel(
    const float* __restrict__ partial, float* __restrict__ rcp, int nb)
{
    const int p = blockIdx.x;
    const int tid = threadIdx.x;
    float s = 0.0f;
    for (int i = tid; i < nb; i += 256) s += partial[(size_t)p * nb + i];
    #pragma unroll
    for (int m = 32; m >= 1; m >>= 1) s += __shfl_xor(s, m);
    __shared__ float red[4];
    if ((tid & 63) == 0) red[tid >> 6] = s;
    __syncthreads();
    if (tid == 0) rcp[p] = 1.0f / (red[0] + red[1] + red[2] + red[3]);
}

// ---------------------------------------------------------------------------
// finalize (R1-proven): w = inv * rcp[p] rescaled IN PLACE, plus
// x_out[n][c] = w[c][n] * x[n][c] via 64x64 LDS transpose.
// ---------------------------------------------------------------------------
__global__ __launch_bounds__(256) void finalize_kernel(
    const float* __restrict__ x, float* __restrict__ w,
    const float* __restrict__ rcp, float* __restrict__ xout, int Nn)
{
    __shared__ float T[64][65];
    const int tid = threadIdx.x;
    const int tx = tid & 15, ty = tid >> 4;
    const int p0 = blockIdx.x * 64, n0 = blockIdx.y * 64;
    #pragma unroll
    for (int rr = 0; rr < 4; ++rr) {
        const int pl = ty + rr * 16;
        const size_t idx = (size_t)(p0 + pl) * Nn + n0 + tx * 4;
        const float4 iv = *(const float4*)(w + idx);
        const float rc = rcp[p0 + pl];
        float4 wv;
        wv.x = iv.x * rc; wv.y = iv.y * rc; wv.z = iv.z * rc; wv.w = iv.w * rc;
        *(float4*)(w + idx) = wv;
        T[tx * 4 + 0][pl] = wv.x;
        T[tx * 4 + 1][pl] = wv.y;
        T[tx * 4 + 2][pl] = wv.z;
        T[tx * 4 + 3][pl] = wv.w;
    }
    __syncthreads();
    #pragma unroll
    for (int rr = 0; rr < 4; ++rr) {
        const int nl = ty + rr * 16;
        const size_t ix = (size_t)(n0 + nl) * 512 + p0 + tx * 4;
        const float4 xv = *(const float4*)(x + ix);
        float4 ov;
        ov.x = xv.x * T[nl][tx * 4 + 0];
        ov.y = xv.y * T[nl][tx * 4 + 1];
        ov.z = xv.z * T[nl][tx * 4 + 2];
        ov.w = xv.w * T[nl][tx * 4 + 3];
        *(float4*)(xout + ix) = ov;
    }
}

// ===========================================================================
// Fallback path (tiny d_ws): R2-verified structure, scratch in x_out half.
// ===========================================================================
template<int MODE>
__global__ __launch_bounds__(256) void gemm_old(
    const ushort_t* __restrict__ pb, const ushort_t* __restrict__ xb,
    const float* __restrict__ p_sq, const float* __restrict__ x_sq,
    const float* __restrict__ rcp,
    float* __restrict__ wout, float* __restrict__ partial, int Nn)
{
    __shared__ __align__(16) char smem[33280];
    ushort_t* As = (ushort_t*)smem;
    ushort_t* Bs = (ushort_t*)(smem + 16384);
    const int tid  = threadIdx.x;
    const int lane = tid & 63, wid = tid >> 6;
    const int wm = wid >> 1, wn = wid & 1;
    const int l15 = lane & 15, l4 = lane >> 4;
    const int m0 = blockIdx.x * 128;
    const int n0 = blockIdx.y * 128;
    f32x4 acc[4][4] = {};
    for (int kt = 0; kt < 512; kt += 64) {
        #pragma unroll
        for (int it = 0; it < 4; ++it) {
            const int cbase = it * 256 + wid * 64;
            const int cid   = cbase + lane;
            const int r     = cid >> 3;
            const int cl    = (cid & 7) ^ (r & 7);
            const ushort_t* ga = pb + (size_t)(m0 + r) * 512 + kt + cl * 8;
            __builtin_amdgcn_global_load_lds((const AS1 unsigned int*)ga,
                (AS3 unsigned int*)(As + cbase * 8), 16, 0, 0);
            const ushort_t* gb = xb + (size_t)(n0 + r) * 512 + kt + cl * 8;
            __builtin_amdgcn_global_load_lds((const AS1 unsigned int*)gb,
                (AS3 unsigned int*)(Bs + cbase * 8), 16, 0, 0);
        }
        __syncthreads();
        #pragma unroll
        for (int kk = 0; kk < 2; ++kk) {
            bf16x8 a[4], b[4];
            #pragma unroll
            for (int mi = 0; mi < 4; ++mi) {
                const int rr = wm * 64 + mi * 16 + l15;
                const int c  = kk * 4 + l4;
                a[mi] = *(const bf16x8*)&As[(rr * 8 + (c ^ (rr & 7))) * 8];
            }
            #pragma unroll
            for (int ni = 0; ni < 4; ++ni) {
                const int rr = wn * 64 + ni * 16 + l15;
                const int c  = kk * 4 + l4;
                b[ni] = *(const bf16x8*)&Bs[(rr * 8 + (c ^ (rr & 7))) * 8];
            }
            #pragma unroll
            for (int mi = 0; mi < 4; ++mi)
                #pragma unroll
                for (int ni = 0; ni < 4; ++ni)
                    acc[mi][ni] = __builtin_amdgcn_mfma_f32_16x16x32_bf16(
                        a[mi], b[ni], acc[mi][ni], 0, 0, 0);
        }
        __syncthreads();
    }
    if (MODE == 0) {
        float psum[4][4] = {};
        #pragma unroll
        for (int mi = 0; mi < 4; ++mi) {
            const int pbase = m0 + wm * 64 + mi * 16 + l4 * 4;
            const f32x4 ps4 = *(const f32x4*)(p_sq + pbase);
            #pragma unroll
            for (int ni = 0; ni < 4; ++ni) {
                const int n = n0 + wn * 64 + ni * 16 + l15;
                const float xs = x_sq[n];
                #pragma unroll
                for (int j = 0; j < 4; ++j) {
                    float d2 = ps4[j] + xs - 2.0f * acc[mi][ni][j];
                    d2 = fmaxf(d2, 1e-20f);
                    psum[mi][j] += 22.62741699796952f * rsqrtf(d2);
                }
            }
        }
        #pragma unroll
        for (int mi = 0; mi < 4; ++mi)
            #pragma unroll
            for (int j = 0; j < 4; ++j) {
                float s = psum[mi][j];
                s += __shfl_xor(s, 1); s += __shfl_xor(s, 2);
                s += __shfl_xor(s, 4); s += __shfl_xor(s, 8);
                psum[mi][j] = s;
            }
        float* sp = (float*)smem;
        if (l15 == 0) {
            #pragma unroll
            for (int mi = 0; mi < 4; ++mi)
                #pragma unroll
                for (int j = 0; j < 4; ++j)
                    sp[(wm * 64 + mi * 16 + l4 * 4 + j) * 2 + wn] = psum[mi][j];
        }
        __syncthreads();
        if (tid < 128)
            partial[(size_t)(m0 + tid) * gridDim.y + blockIdx.y] =
                sp[tid * 2] + sp[tid * 2 + 1];
    } else {
        #pragma unroll
        for (int mi = 0; mi < 4; ++mi) {
            const int pbase = m0 + wm * 64 + mi * 16 + l4 * 4;
            const f32x4 ps4 = *(const f32x4*)(p_sq + pbase);
            const f32x4 rc4 = *(const f32x4*)(rcp + pbase);
            #pragma unroll
            for (int ni = 0; ni < 4; ++ni) {
                const int n = n0 + wn * 64 + ni * 16 + l15;
                const float xs = x_sq[n];
                #pragma unroll
                for (int j = 0; j < 4; ++j) {
                    float d2 = ps4[j] + xs - 2.0f * acc[mi][ni][j];
                    d2 = fmaxf(d2, 1e-20f);
                    wout[(size_t)(pbase + j) * Nn + n] =
                        22.62741699796952f * rsqrtf(d2) * rc4[j];
                }
            }
        }
    }
}

__global__ __launch_bounds__(256) void finalize2_kernel(
    const float* __restrict__ x, const float* __restrict__ w,
    float* __restrict__ xout, int Nn)
{
    __shared__ float T[64][65];
    const int tid = threadIdx.x;
    const int tx = tid & 15, ty = tid >> 4;
    const int p0 = blockIdx.x * 64, n0 = blockIdx.y * 64;
    #pragma unroll
    for (int rr = 0; rr < 4; ++rr) {
        const int pl = ty + rr * 16;
        const f32x4 wv = *(const f32x4*)(w + (size_t)(p0 + pl) * Nn + n0 + tx * 4);
        T[tx * 4 + 0][pl] = wv[0];
        T[tx * 4 + 1][pl] = wv[1];
        T[tx * 4 + 2][pl] = wv[2];
        T[tx * 4 + 3][pl] = wv[3];
    }
    __syncthreads();
    #pragma unroll
    for (int rr = 0; rr < 4; ++rr) {
        const int nl = ty + rr * 16;
        const size_t ix = (size_t)(n0 + nl) * 512 + p0 + tx * 4;
        const f32x4 xv = *(const f32x4*)(x + ix);
        f32x4 ov;
        ov[0] = xv[0] * T[nl][tx * 4 + 0];
        ov[1] = xv[1] * T[nl][tx * 4 + 1];
        ov[2] = xv[2] * T[nl][tx * 4 + 2];
        ov[3] = xv[3] * T[nl][tx * 4 + 3];
        *(f32x4*)(xout + ix) = ov;
    }
}

// ---------------------------------------------------------------------------
// Host launch.
//  main (ws >= ~1.8 MB): prep_p -> gemm_inv (single-buffer, inv f32 into
//  wout region) -> rowsum -> finalize (in-place rescale + transpose x_out).
//  fallback: R2 structure.
// ---------------------------------------------------------------------------
extern "C" void kernel_launch(void* const* d_in, const int* in_sizes, int n_in,
                              void* d_out, int out_size, void* d_ws, size_t ws_size,
                              hipStream_t stream)
{
    const float* x     = (const float*)d_in[0];
    const float* proto = (const float*)d_in[1];
    const int C = 512, P = 512;
    const int N = in_sizes[0] / C;            // 65536
    const int NB = N / 128;

    float* xout = (float*)d_out;              // N*C floats
    float* wout = xout + (size_t)N * C;       // P*N floats (inv, then w)

    const size_t pbf_b = (size_t)P * C * 2;   // 512 KiB
    const size_t need  = pbf_b + (size_t)P * 4 + (size_t)N * 4
                       + (size_t)P * NB * 4 + (size_t)P * 4;   // ~1.8 MiB

    if (ws_size >= need) {
        char* scr = (char*)d_ws;
        ushort_t* pbf  = (ushort_t*)scr;
        float*    p_sq = (float*)(scr + pbf_b);
        float*    part = p_sq + P;
        float*    rcp  = part + (size_t)P * NB;

        prep_kernel<<<P / 4, 256, 0, stream>>>(proto, pbf, p_sq);
        gemm_inv<<<dim3(P / 128, NB), 256, 0, stream>>>(
            pbf, x, p_sq, wout, part, N);
        rowsum_kernel<<<P, 256, 0, stream>>>(part, rcp, NB);
        finalize_kernel<<<dim3(P / 64, N / 64), 256, 0, stream>>>(
            x, wout, rcp, xout, N);
    } else {
        char* scr = (char*)d_out;             // scratch inside x_out half
        const size_t xb_b = (size_t)N * C * 2;
        ushort_t* xb   = (ushort_t*)scr;
        ushort_t* pbf  = (ushort_t*)(scr + xb_b);
        float*    x_sq = (float*)(scr + xb_b + pbf_b);
        float*    p_sq = x_sq + N;
        float*    part = p_sq + P;
        float*    rcp  = (float*)d_ws;

        prep_kernel<<<N / 4, 256, 0, stream>>>(x, xb, x_sq);
        prep_kernel<<<P / 4, 256, 0, stream>>>(proto, pbf, p_sq);
        gemm_old<0><<<dim3(P / 128, NB), 256, 0, stream>>>(
            pbf, xb, p_sq, x_sq, nullptr, nullptr, part, N);
        rowsum_kernel<<<P, 256, 0, stream>>>(part, rcp, NB);
        gemm_old<2><<<dim3(P / 128, NB), 256, 0, stream>>>(
            pbf, xb, p_sq, x_sq, rcp, wout, nullptr, N);
        finalize2_kernel<<<dim3(P / 64, N / 64), 256, 0, stream>>>(
            x, wout, xout, N);
    }
}

// Round 8
// 171.754 us; speedup vs baseline: 1.7650x; 1.2211x over previous
//
#include <hip/hip_runtime.h>
#include <hip/hip_bf16.h>

typedef unsigned short ushort_t;
typedef __attribute__((ext_vector_type(8))) short bf16x8;
typedef __attribute__((ext_vector_type(4))) float f32x4;
typedef __attribute__((ext_vector_type(8))) unsigned short u16x8;

#define AS1 __attribute__((address_space(1)))
#define AS3 __attribute__((address_space(3)))

// RNE float -> bf16 (scalar, used in prep/fallback only)
static __device__ __forceinline__ unsigned short f2bf(float f) {
    unsigned u = __float_as_uint(f);
    u += 0x7fffu + ((u >> 16) & 1u);
    return (unsigned short)(u >> 16);
}

// packed RNE float8 -> bf16x8 via v_cvt_pk_bf16_f32 (compiler-emitted)
static __device__ __forceinline__ u16x8 cvt8(const float4 f0, const float4 f1) {
    union { __hip_bfloat162 h2[4]; u16x8 v; } u;
    u.h2[0] = __float22bfloat162_rn(make_float2(f0.x, f0.y));
    u.h2[1] = __float22bfloat162_rn(make_float2(f0.z, f0.w));
    u.h2[2] = __float22bfloat162_rn(make_float2(f1.x, f1.y));
    u.h2[3] = __float22bfloat162_rn(make_float2(f1.z, f1.w));
    return u.v;
}

// ---------------------------------------------------------------------------
// prep: per-row sum-of-squares + fp32 -> bf16. One wave per row (C=512).
// ---------------------------------------------------------------------------
__global__ __launch_bounds__(256) void prep_kernel(
    const float* __restrict__ src, ushort_t* __restrict__ dst,
    float* __restrict__ sq)
{
    const int row  = blockIdx.x * 4 + (threadIdx.x >> 6);
    const int lane = threadIdx.x & 63;
    const float4* s = (const float4*)(src + (size_t)row * 512);
    float4 v0 = s[lane * 2 + 0];
    float4 v1 = s[lane * 2 + 1];
    float ss = v0.x*v0.x + v0.y*v0.y + v0.z*v0.z + v0.w*v0.w
             + v1.x*v1.x + v1.y*v1.y + v1.z*v1.z + v1.w*v1.w;
    #pragma unroll
    for (int m = 32; m >= 1; m >>= 1) ss += __shfl_xor(ss, m);
    if (lane == 0) sq[row] = ss;
    *(u16x8*)(dst + (size_t)row * 512 + lane * 8) = cvt8(v0, v1);
}

// ---------------------------------------------------------------------------
// Main path GEMM (R4 body): cross (M=512, N=65536, K=512), 128x128 tile,
// BK=64, chunked XCD swizzle, A via global_load_lds w=16 (inverse-swizzled
// source), B (x f32) reg-staged -> PACKED cvt_pk bf16 -> swizzled ds_write.
// MODE 0: inline x_sq + deterministic partial row sums of inv-distance.
// MODE 1: w = inv*rcp -> weights; in-LDS transpose -> x_out.
// ---------------------------------------------------------------------------
template<int MODE>
__global__ __launch_bounds__(256, 4) void gemm_f32(
    const ushort_t* __restrict__ pb, const float* __restrict__ x,
    const float* __restrict__ p_sq, float* __restrict__ x_sq,
    const float* __restrict__ rcp, float* __restrict__ wout,
    float* __restrict__ xout, float* __restrict__ partial, int Nn)
{
    __shared__ __align__(16) char smem[33280];   // As+Bs (32KB) / Tr[128][65]
    ushort_t* As = (ushort_t*)smem;
    ushort_t* Bs = (ushort_t*)(smem + 16384);

    const int tid  = threadIdx.x;
    const int lane = tid & 63, wid = tid >> 6;
    const int wm = wid >> 1, wn = wid & 1;
    const int l15 = lane & 15, l4 = lane >> 4;

    // chunked XCD swizzle (bijective when nwg % 8 == 0)
    const int nwg = gridDim.x * gridDim.y;          // 4 * NB
    const int w   = blockIdx.x + gridDim.x * blockIdx.y;
    int orig = w;
    if ((nwg & 7) == 0) orig = (w & 7) * (nwg >> 3) + (w >> 3);
    const int m0 = (orig & 3) * 128;                // gridDim.x == 4 (P=512)
    const int n0 = (orig >> 2) * 128;
    const int by = orig >> 2;

    f32x4 acc[4][4] = {};
    float ssq[4] = {0.f, 0.f, 0.f, 0.f};            // MODE 0: x row sumsq

    for (int kt = 0; kt < 512; kt += 64) {
        // A: global_load_lds, linear LDS dest + inverse-swizzled source
        #pragma unroll
        for (int it = 0; it < 4; ++it) {
            const int cbase = it * 256 + wid * 64;
            const int cid   = cbase + lane;
            const int r     = cid >> 3;
            const int cl    = (cid & 7) ^ (r & 7);
            const ushort_t* ga = pb + (size_t)(m0 + r) * 512 + kt + cl * 8;
            __builtin_amdgcn_global_load_lds((const AS1 unsigned int*)ga,
                (AS3 unsigned int*)(As + cbase * 8), 16, 0, 0);
        }
        // B: f32 coalesced load -> packed cvt bf16 -> swizzled ds_write (16B)
        #pragma unroll
        for (int it = 0; it < 4; ++it) {
            const int g  = it * 256 + tid;
            const int r  = g >> 3;
            const int cl = g & 7;
            const float4* src = (const float4*)(x + (size_t)(n0 + r) * 512 + kt + cl * 8);
            const float4 f0 = src[0];
            const float4 f1 = src[1];
            if (MODE == 0)
                ssq[it] += f0.x*f0.x + f0.y*f0.y + f0.z*f0.z + f0.w*f0.w
                         + f1.x*f1.x + f1.y*f1.y + f1.z*f1.z + f1.w*f1.w;
            *(u16x8*)&Bs[((size_t)(r * 8 + (cl ^ (r & 7)))) * 8] = cvt8(f0, f1);
        }
        __syncthreads();
        #pragma unroll
        for (int kk = 0; kk < 2; ++kk) {
            bf16x8 a[4], b[4];
            #pragma unroll
            for (int mi = 0; mi < 4; ++mi) {
                const int rr = wm * 64 + mi * 16 + l15;
                const int c  = kk * 4 + l4;
                a[mi] = *(const bf16x8*)&As[(rr * 8 + (c ^ (rr & 7))) * 8];
            }
            #pragma unroll
            for (int ni = 0; ni < 4; ++ni) {
                const int rr = wn * 64 + ni * 16 + l15;
                const int c  = kk * 4 + l4;
                b[ni] = *(const bf16x8*)&Bs[(rr * 8 + (c ^ (rr & 7))) * 8];
            }
            #pragma unroll
            for (int mi = 0; mi < 4; ++mi)
                #pragma unroll
                for (int ni = 0; ni < 4; ++ni)
                    acc[mi][ni] = __builtin_amdgcn_mfma_f32_16x16x32_bf16(
                        a[mi], b[ni], acc[mi][ni], 0, 0, 0);
        }
        __syncthreads();
    }

    // D frag (m89): col = lane&15 (-> n), row = (lane>>4)*4 + j (-> p)
    if (MODE == 0) {
        // finish inline x_sq: 8 consecutive lanes share one x row
        float* xsq_s = (float*)(smem + 16384);      // 128 floats (Bs region)
        #pragma unroll
        for (int it = 0; it < 4; ++it) {
            float s = ssq[it];
            s += __shfl_xor(s, 1); s += __shfl_xor(s, 2); s += __shfl_xor(s, 4);
            if ((tid & 7) == 0) {
                const int r = it * 32 + (tid >> 3);
                xsq_s[r] = s;
                x_sq[n0 + r] = s;    // all 4 m-sibling blocks write same value
            }
        }
        __syncthreads();

        float psum[4][4] = {};
        #pragma unroll
        for (int mi = 0; mi < 4; ++mi) {
            const int pbase = m0 + wm * 64 + mi * 16 + l4 * 4;
            const f32x4 ps4 = *(const f32x4*)(p_sq + pbase);
            #pragma unroll
            for (int ni = 0; ni < 4; ++ni) {
                const int nl = wn * 64 + ni * 16 + l15;
                const float xs = xsq_s[nl];
                #pragma unroll
                for (int j = 0; j < 4; ++j) {
                    float d2 = ps4[j] + xs - 2.0f * acc[mi][ni][j];
                    d2 = fmaxf(d2, 1e-20f);
                    psum[mi][j] += 22.62741699796952f * rsqrtf(d2);
                }
            }
        }
        #pragma unroll
        for (int mi = 0; mi < 4; ++mi)
            #pragma unroll
            for (int j = 0; j < 4; ++j) {
                float s = psum[mi][j];
                s += __shfl_xor(s, 1); s += __shfl_xor(s, 2);
                s += __shfl_xor(s, 4); s += __shfl_xor(s, 8);
                psum[mi][j] = s;
            }
        float* sp = (float*)smem;  // [128 rows][2 wn] (As region)
        if (l15 == 0) {
            #pragma unroll
            for (int mi = 0; mi < 4; ++mi)
                #pragma unroll
                for (int j = 0; j < 4; ++j)
                    sp[(wm * 64 + mi * 16 + l4 * 4 + j) * 2 + wn] = psum[mi][j];
        }
        __syncthreads();
        if (tid < 128)
            partial[(size_t)(m0 + tid) * gridDim.y + by] =
                sp[tid * 2] + sp[tid * 2 + 1];
    } else {
        // w = inv * rcp[p]; write weights; keep w in acc for the transpose.
        #pragma unroll
        for (int mi = 0; mi < 4; ++mi) {
            const int pbase = m0 + wm * 64 + mi * 16 + l4 * 4;
            const f32x4 ps4 = *(const f32x4*)(p_sq + pbase);
            const f32x4 rc4 = *(const f32x4*)(rcp + pbase);
            #pragma unroll
            for (int ni = 0; ni < 4; ++ni) {
                const int n = n0 + wn * 64 + ni * 16 + l15;
                const float xs = x_sq[n];
                #pragma unroll
                for (int j = 0; j < 4; ++j) {
                    float d2 = ps4[j] + xs - 2.0f * acc[mi][ni][j];
                    d2 = fmaxf(d2, 1e-20f);
                    const float w5 = 22.62741699796952f * rsqrtf(d2) * rc4[j];
                    acc[mi][ni][j] = w5;
                    wout[(size_t)(pbase + j) * Nn + n] = w5;
                }
            }
        }
        // x_out[n][c] = w[c][n] * x[n][c], c in this block's p-range.
        float (*Tr)[65] = (float(*)[65])smem;
        const int tx = tid & 15, ty = tid >> 4;
        #pragma unroll
        for (int h = 0; h < 2; ++h) {
            __syncthreads();
            if (wm == h) {
                #pragma unroll
                for (int mi = 0; mi < 4; ++mi)
                    #pragma unroll
                    for (int ni = 0; ni < 4; ++ni)
                        #pragma unroll
                        for (int j = 0; j < 4; ++j)
                            Tr[wn * 64 + ni * 16 + l15][mi * 16 + l4 * 4 + j]
                                = acc[mi][ni][j];
            }
            __syncthreads();
            #pragma unroll
            for (int rr = 0; rr < 8; ++rr) {
                const int nl = ty + rr * 16;
                const size_t gx = (size_t)(n0 + nl) * 512 + m0 + h * 64 + tx * 4;
                const float4 xv = *(const float4*)(x + gx);
                f32x4 ov;
                ov[0] = xv.x * Tr[nl][tx * 4 + 0];
                ov[1] = xv.y * Tr[nl][tx * 4 + 1];
                ov[2] = xv.z * Tr[nl][tx * 4 + 2];
                ov[3] = xv.w * Tr[nl][tx * 4 + 3];
                *(f32x4*)(xout + gx) = ov;
            }
        }
    }
}

// ---------------------------------------------------------------------------
// rowsum: partials per prototype -> reciprocal (deterministic tree)
// ---------------------------------------------------------------------------
__global__ __launch_bounds__(256) void rowsum_kernel(
    const float* __restrict__ partial, float* __restrict__ rcp, int nb)
{
    const int p = blockIdx.x;
    const int tid = threadIdx.x;
    float s = 0.0f;
    for (int i = tid; i < nb; i += 256) s += partial[(size_t)p * nb + i];
    #pragma unroll
    for (int m = 32; m >= 1; m >>= 1) s += __shfl_xor(s, m);
    __shared__ float red[4];
    if ((tid & 63) == 0) red[tid >> 6] = s;
    __syncthreads();
    if (tid == 0) rcp[p] = 1.0f / (red[0] + red[1] + red[2] + red[3]);
}

// ===========================================================================
// Fallback path (tiny d_ws): R2-verified structure, scratch in x_out half.
// ===========================================================================
template<int MODE>
__global__ __launch_bounds__(256) void gemm_old(
    const ushort_t* __restrict__ pb, const ushort_t* __restrict__ xb,
    const float* __restrict__ p_sq, const float* __restrict__ x_sq,
    const float* __restrict__ rcp,
    float* __restrict__ wout, float* __restrict__ partial, int Nn)
{
    __shared__ __align__(16) char smem[33280];
    ushort_t* As = (ushort_t*)smem;
    ushort_t* Bs = (ushort_t*)(smem + 16384);
    const int tid  = threadIdx.x;
    const int lane = tid & 63, wid = tid >> 6;
    const int wm = wid >> 1, wn = wid & 1;
    const int l15 = lane & 15, l4 = lane >> 4;
    const int m0 = blockIdx.x * 128;
    const int n0 = blockIdx.y * 128;
    f32x4 acc[4][4] = {};
    for (int kt = 0; kt < 512; kt += 64) {
        #pragma unroll
        for (int it = 0; it < 4; ++it) {
            const int cbase = it * 256 + wid * 64;
            const int cid   = cbase + lane;
            const int r     = cid >> 3;
            const int cl    = (cid & 7) ^ (r & 7);
            const ushort_t* ga = pb + (size_t)(m0 + r) * 512 + kt + cl * 8;
            __builtin_amdgcn_global_load_lds((const AS1 unsigned int*)ga,
                (AS3 unsigned int*)(As + cbase * 8), 16, 0, 0);
            const ushort_t* gb = xb + (size_t)(n0 + r) * 512 + kt + cl * 8;
            __builtin_amdgcn_global_load_lds((const AS1 unsigned int*)gb,
                (AS3 unsigned int*)(Bs + cbase * 8), 16, 0, 0);
        }
        __syncthreads();
        #pragma unroll
        for (int kk = 0; kk < 2; ++kk) {
            bf16x8 a[4], b[4];
            #pragma unroll
            for (int mi = 0; mi < 4; ++mi) {
                const int rr = wm * 64 + mi * 16 + l15;
                const int c  = kk * 4 + l4;
                a[mi] = *(const bf16x8*)&As[(rr * 8 + (c ^ (rr & 7))) * 8];
            }
            #pragma unroll
            for (int ni = 0; ni < 4; ++ni) {
                const int rr = wn * 64 + ni * 16 + l15;
                const int c  = kk * 4 + l4;
                b[ni] = *(const bf16x8*)&Bs[(rr * 8 + (c ^ (rr & 7))) * 8];
            }
            #pragma unroll
            for (int mi = 0; mi < 4; ++mi)
                #pragma unroll
                for (int ni = 0; ni < 4; ++ni)
                    acc[mi][ni] = __builtin_amdgcn_mfma_f32_16x16x32_bf16(
                        a[mi], b[ni], acc[mi][ni], 0, 0, 0);
        }
        __syncthreads();
    }
    if (MODE == 0) {
        float psum[4][4] = {};
        #pragma unroll
        for (int mi = 0; mi < 4; ++mi) {
            const int pbase = m0 + wm * 64 + mi * 16 + l4 * 4;
            const f32x4 ps4 = *(const f32x4*)(p_sq + pbase);
            #pragma unroll
            for (int ni = 0; ni < 4; ++ni) {
                const int n = n0 + wn * 64 + ni * 16 + l15;
                const float xs = x_sq[n];
                #pragma unroll
                for (int j = 0; j < 4; ++j) {
                    float d2 = ps4[j] + xs - 2.0f * acc[mi][ni][j];
                    d2 = fmaxf(d2, 1e-20f);
                    psum[mi][j] += 22.62741699796952f * rsqrtf(d2);
                }
            }
        }
        #pragma unroll
        for (int mi = 0; mi < 4; ++mi)
            #pragma unroll
            for (int j = 0; j < 4; ++j) {
                float s = psum[mi][j];
                s += __shfl_xor(s, 1); s += __shfl_xor(s, 2);
                s += __shfl_xor(s, 4); s += __shfl_xor(s, 8);
                psum[mi][j] = s;
            }
        float* sp = (float*)smem;
        if (l15 == 0) {
            #pragma unroll
            for (int mi = 0; mi < 4; ++mi)
                #pragma unroll
                for (int j = 0; j < 4; ++j)
                    sp[(wm * 64 + mi * 16 + l4 * 4 + j) * 2 + wn] = psum[mi][j];
        }
        __syncthreads();
        if (tid < 128)
            partial[(size_t)(m0 + tid) * gridDim.y + blockIdx.y] =
                sp[tid * 2] + sp[tid * 2 + 1];
    } else {
        #pragma unroll
        for (int mi = 0; mi < 4; ++mi) {
            const int pbase = m0 + wm * 64 + mi * 16 + l4 * 4;
            const f32x4 ps4 = *(const f32x4*)(p_sq + pbase);
            const f32x4 rc4 = *(const f32x4*)(rcp + pbase);
            #pragma unroll
            for (int ni = 0; ni < 4; ++ni) {
                const int n = n0 + wn * 64 + ni * 16 + l15;
                const float xs = x_sq[n];
                #pragma unroll
                for (int j = 0; j < 4; ++j) {
                    float d2 = ps4[j] + xs - 2.0f * acc[mi][ni][j];
                    d2 = fmaxf(d2, 1e-20f);
                    wout[(size_t)(pbase + j) * Nn + n] =
                        22.62741699796952f * rsqrtf(d2) * rc4[j];
                }
            }
        }
    }
}

__global__ __launch_bounds__(256) void finalize2_kernel(
    const float* __restrict__ x, const float* __restrict__ w,
    float* __restrict__ xout, int Nn)
{
    __shared__ float T[64][65];
    const int tid = threadIdx.x;
    const int tx = tid & 15, ty = tid >> 4;
    const int p0 = blockIdx.x * 64, n0 = blockIdx.y * 64;
    #pragma unroll
    for (int rr = 0; rr < 4; ++rr) {
        const int pl = ty + rr * 16;
        const f32x4 wv = *(const f32x4*)(w + (size_t)(p0 + pl) * Nn + n0 + tx * 4);
        T[tx * 4 + 0][pl] = wv[0];
        T[tx * 4 + 1][pl] = wv[1];
        T[tx * 4 + 2][pl] = wv[2];
        T[tx * 4 + 3][pl] = wv[3];
    }
    __syncthreads();
    #pragma unroll
    for (int rr = 0; rr < 4; ++rr) {
        const int nl = ty + rr * 16;
        const size_t ix = (size_t)(n0 + nl) * 512 + p0 + tx * 4;
        const f32x4 xv = *(const f32x4*)(x + ix);
        f32x4 ov;
        ov[0] = xv[0] * T[nl][tx * 4 + 0];
        ov[1] = xv[1] * T[nl][tx * 4 + 1];
        ov[2] = xv[2] * T[nl][tx * 4 + 2];
        ov[3] = xv[3] * T[nl][tx * 4 + 3];
        *(f32x4*)(xout + ix) = ov;
    }
}

// ---------------------------------------------------------------------------
// Host launch.
//  main (ws >= ~1.8 MB): R4 structure — gemm0 (sums + inline x_sq), rowsum,
//  gemm1 fused (weights + x_out). Staging cvt now packed (v_cvt_pk_bf16_f32).
//  fallback: R2 structure.
// ---------------------------------------------------------------------------
extern "C" void kernel_launch(void* const* d_in, const int* in_sizes, int n_in,
                              void* d_out, int out_size, void* d_ws, size_t ws_size,
                              hipStream_t stream)
{
    const float* x     = (const float*)d_in[0];
    const float* proto = (const float*)d_in[1];
    const int C = 512, P = 512;
    const int N = in_sizes[0] / C;            // 65536
    const int NB = N / 128;

    float* xout = (float*)d_out;              // N*C floats
    float* wout = xout + (size_t)N * C;       // P*N floats

    const size_t pbf_b = (size_t)P * C * 2;   // 512 KiB
    const size_t need  = pbf_b + (size_t)P * 4 + (size_t)N * 4
                       + (size_t)P * NB * 4 + (size_t)P * 4;   // ~1.8 MiB

    if (ws_size >= need) {
        char* scr = (char*)d_ws;
        ushort_t* pbf  = (ushort_t*)scr;
        float*    p_sq = (float*)(scr + pbf_b);
        float*    x_sq = p_sq + P;
        float*    part = x_sq + N;
        float*    rcp  = part + (size_t)P * NB;

        prep_kernel<<<P / 4, 256, 0, stream>>>(proto, pbf, p_sq);
        gemm_f32<0><<<dim3(P / 128, NB), 256, 0, stream>>>(
            pbf, x, p_sq, x_sq, nullptr, nullptr, nullptr, part, N);
        rowsum_kernel<<<P, 256, 0, stream>>>(part, rcp, NB);
        gemm_f32<1><<<dim3(P / 128, NB), 256, 0, stream>>>(
            pbf, x, p_sq, x_sq, rcp, wout, xout, nullptr, N);
    } else {
        char* scr = (char*)d_out;             // scratch inside x_out half
        const size_t xb_b = (size_t)N * C * 2;
        ushort_t* xb   = (ushort_t*)scr;
        ushort_t* pbf  = (ushort_t*)(scr + xb_b);
        float*    x_sq = (float*)(scr + xb_b + pbf_b);
        float*    p_sq = x_sq + N;
        float*    part = p_sq + P;
        float*    rcp  = (float*)d_ws;

        prep_kernel<<<N / 4, 256, 0, stream>>>(x, xb, x_sq);
        prep_kernel<<<P / 4, 256, 0, stream>>>(proto, pbf, p_sq);
        gemm_old<0><<<dim3(P / 128, NB), 256, 0, stream>>>(
            pbf, xb, p_sq, x_sq, nullptr, nullptr, part, N);
        rowsum_kernel<<<P, 256, 0, stream>>>(part, rcp, NB);
        gemm_old<2><<<dim3(P / 128, NB), 256, 0, stream>>>(
            pbf, xb, p_sq, x_sq, rcp, wout, nullptr, N);
        finalize2_kernel<<<dim3(P / 64, N / 64), 256, 0, stream>>>(
            x, wout, xout, N);
    }
}